// Round 1
// baseline (392.898 us; speedup 1.0000x reference)
//
#include <hip/hip_runtime.h>
#include <math.h>

#define NEG_SLOPE 0.2f
#define LN_EPS 1e-5f

// ---------------------------------------------------------------------------
// k_proj: h = x @ W  ([N,128]x[128,128]), fused per-node attention scalars
//   ssrc[n][head] = sum_d h[n,head,d]*a_src[d],  sdst likewise.
// Block = 256 threads: c = t&31 (col quad, 4 cols each), rg = t>>5 (row quad,
// 4 rows each) -> 32 rows x 128 cols per block. W staged in LDS in two 64-row
// halves (32 KB) + transposed x tile (18 KB) => ~50 KB LDS, 3 blocks/CU.
// Inner loop: 2x ds_read_b128 -> 16 FMA (VALU-bound by design).
// ---------------------------------------------------------------------------
__global__ __launch_bounds__(256) void k_proj(
    const float* __restrict__ x, const float* __restrict__ W,
    const float* __restrict__ a_src, const float* __restrict__ a_dst,
    float* __restrict__ h, float* __restrict__ ssrc, float* __restrict__ sdst,
    int n_nodes)
{
  __shared__ __align__(16) float wlds[64 * 128];   // one k-half of W
  __shared__ __align__(16) float xt[128 * 36];     // x transposed [k][row], stride 36 (pad: banks + 16B align)
  const int t  = threadIdx.x;
  const int c  = t & 31;      // col group: cols 4c..4c+3
  const int rg = t >> 5;      // row group: rows rg*4..rg*4+3
  const int base = blockIdx.x * 32;

  // per-thread a_src/a_dst slice (cols 4c..4c+3 -> d = 4*(c&7)+j, head = c>>3)
  const int dl = (c & 7) * 4;
  const float as0 = a_src[dl+0], as1 = a_src[dl+1], as2 = a_src[dl+2], as3 = a_src[dl+3];
  const float ad0 = a_dst[dl+0], ad1 = a_dst[dl+1], ad2 = a_dst[dl+2], ad3 = a_dst[dl+3];

  // stage x tile transposed: xt[k][row_local]
  for (int ii = t * 4; ii < 32 * 128; ii += 1024) {
    const int rl = ii >> 7;
    const int k0 = ii & 127;
    const int grow = base + rl;
    float4 v = make_float4(0.f, 0.f, 0.f, 0.f);
    if (grow < n_nodes) v = *(const float4*)(x + (size_t)grow * 128 + k0);
    xt[(k0+0)*36 + rl] = v.x;
    xt[(k0+1)*36 + rl] = v.y;
    xt[(k0+2)*36 + rl] = v.z;
    xt[(k0+3)*36 + rl] = v.w;
  }

  float acc[4][4] = {};
  for (int half = 0; half < 2; ++half) {
    __syncthreads();                       // protect wlds from previous half
    // load W rows [half*64, half*64+64)
    for (int i = t * 4; i < 64 * 128; i += 1024)
      *(float4*)(wlds + i) = *(const float4*)(W + half * 64 * 128 + i);
    __syncthreads();
    #pragma unroll 8
    for (int k2 = 0; k2 < 64; ++k2) {
      const int k = half * 64 + k2;
      const float4 wv = *(const float4*)(&wlds[k2 * 128 + 4 * c]);
      const float4 xv = *(const float4*)(&xt[k * 36 + rg * 4]);
      acc[0][0] = fmaf(xv.x, wv.x, acc[0][0]);
      acc[0][1] = fmaf(xv.x, wv.y, acc[0][1]);
      acc[0][2] = fmaf(xv.x, wv.z, acc[0][2]);
      acc[0][3] = fmaf(xv.x, wv.w, acc[0][3]);
      acc[1][0] = fmaf(xv.y, wv.x, acc[1][0]);
      acc[1][1] = fmaf(xv.y, wv.y, acc[1][1]);
      acc[1][2] = fmaf(xv.y, wv.z, acc[1][2]);
      acc[1][3] = fmaf(xv.y, wv.w, acc[1][3]);
      acc[2][0] = fmaf(xv.z, wv.x, acc[2][0]);
      acc[2][1] = fmaf(xv.z, wv.y, acc[2][1]);
      acc[2][2] = fmaf(xv.z, wv.z, acc[2][2]);
      acc[2][3] = fmaf(xv.z, wv.w, acc[2][3]);
      acc[3][0] = fmaf(xv.w, wv.x, acc[3][0]);
      acc[3][1] = fmaf(xv.w, wv.y, acc[3][1]);
      acc[3][2] = fmaf(xv.w, wv.z, acc[3][2]);
      acc[3][3] = fmaf(xv.w, wv.w, acc[3][3]);
    }
  }

  // epilogue: store h, reduce attention scalars across 8-lane col groups
  #pragma unroll
  for (int rr = 0; rr < 4; ++rr) {
    const int row = base + rg * 4 + rr;          // uniform across the 32-lane row group
    if (row < n_nodes)
      *(float4*)(h + (size_t)row * 128 + 4 * c) =
          make_float4(acc[rr][0], acc[rr][1], acc[rr][2], acc[rr][3]);
    float ps = acc[rr][0]*as0 + acc[rr][1]*as1 + acc[rr][2]*as2 + acc[rr][3]*as3;
    float pd = acc[rr][0]*ad0 + acc[rr][1]*ad1 + acc[rr][2]*ad2 + acc[rr][3]*ad3;
    #pragma unroll
    for (int off = 1; off < 8; off <<= 1) {
      ps += __shfl_xor(ps, off, 8);
      pd += __shfl_xor(pd, off, 8);
    }
    if ((c & 7) == 0 && row < n_nodes) {
      const int head = c >> 3;
      ssrc[row * 4 + head] = ps;
      sdst[row * 4 + head] = pd;
    }
  }
}

// ---------------------------------------------------------------------------
// CSR build: count -> 3-kernel exclusive scan -> fill (stores src node id)
// ---------------------------------------------------------------------------
__global__ void k_count(const int* __restrict__ dst, int* __restrict__ counts, int n_edges) {
  const int e = blockIdx.x * 256 + threadIdx.x;
  if (e < n_edges) atomicAdd(&counts[dst[e]], 1);
}

__global__ __launch_bounds__(256) void k_scan1(const int* __restrict__ counts,
    int* __restrict__ row_start, int* __restrict__ blk_sums, int n) {
  __shared__ int sdata[256];
  const int t = threadIdx.x;
  const int base = blockIdx.x * 1024 + t * 4;
  const int v0 = (base+0 < n) ? counts[base+0] : 0;
  const int v1 = (base+1 < n) ? counts[base+1] : 0;
  const int v2 = (base+2 < n) ? counts[base+2] : 0;
  const int v3 = (base+3 < n) ? counts[base+3] : 0;
  const int tsum = v0 + v1 + v2 + v3;
  sdata[t] = tsum;
  __syncthreads();
  for (int off = 1; off < 256; off <<= 1) {
    const int addv = (t >= off) ? sdata[t - off] : 0;
    __syncthreads();
    sdata[t] += addv;
    __syncthreads();
  }
  int excl = sdata[t] - tsum;
  if (base+0 < n) row_start[base+0] = excl;  excl += v0;
  if (base+1 < n) row_start[base+1] = excl;  excl += v1;
  if (base+2 < n) row_start[base+2] = excl;  excl += v2;
  if (base+3 < n) row_start[base+3] = excl;
  if (t == 255) blk_sums[blockIdx.x] = sdata[255];
}

__global__ __launch_bounds__(128) void k_scan2(int* __restrict__ blk_sums, int nblk,
    int* __restrict__ row_start, int n, int n_edges) {
  __shared__ int sd[128];
  const int t = threadIdx.x;
  const int v = (t < nblk) ? blk_sums[t] : 0;
  sd[t] = v;
  __syncthreads();
  for (int off = 1; off < 128; off <<= 1) {
    const int addv = (t >= off) ? sd[t - off] : 0;
    __syncthreads();
    sd[t] += addv;
    __syncthreads();
  }
  if (t < nblk) blk_sums[t] = sd[t] - v;   // exclusive block offsets
  if (t == 0) row_start[n] = n_edges;
}

__global__ __launch_bounds__(256) void k_scan3(int* __restrict__ row_start,
    const int* __restrict__ blk_sums, int* __restrict__ cursor, int n) {
  const int off = blk_sums[blockIdx.x];
  const int base = blockIdx.x * 1024 + threadIdx.x * 4;
  #pragma unroll
  for (int j = 0; j < 4; ++j) {
    const int i = base + j;
    if (i < n) {
      const int vfin = row_start[i] + off;
      row_start[i] = vfin;
      cursor[i] = vfin;
    }
  }
}

__global__ void k_fill(const int* __restrict__ src, const int* __restrict__ dst,
                       int* __restrict__ cursor, int* __restrict__ csr_src, int n_edges) {
  const int e = blockIdx.x * 256 + threadIdx.x;
  if (e < n_edges) {
    const int pos = atomicAdd(&cursor[dst[e]], 1);
    csr_src[pos] = src[e];
  }
}

// ---------------------------------------------------------------------------
// k_agg: one block (128 thr) per dst node. t -> (head = t>>5, d = t&31).
// Phase A: lane-distributed online softmax stats over in-edges, shfl-merged
//          within each 32-lane head group.
// Phase B: alpha-weighted gather-sum of h[src] (coalesced 512 B per edge).
// Epilogue: residual + LayerNorm (block reduce) + ELU -> d_out. No atomics.
// ---------------------------------------------------------------------------
__global__ __launch_bounds__(128) void k_agg(
    const float* __restrict__ h, const float* __restrict__ ssrc,
    const float* __restrict__ sdst, const int* __restrict__ row_start,
    const int* __restrict__ csr_src, const float* __restrict__ x,
    const float* __restrict__ gamma, const float* __restrict__ beta,
    float* __restrict__ out)
{
  const int node = blockIdx.x;
  const int t    = threadIdx.x;
  const int head = t >> 5;
  const int lane = t & 31;
  const int beg  = row_start[node];
  const int end  = row_start[node + 1];
  const int deg  = end - beg;
  const float sd = sdst[node * 4 + head];

  // Phase A: per-lane online max/sum over strided edge subset
  float m = -INFINITY, l = 0.f, s_keep = 0.f;
  for (int i = lane; i < deg; i += 32) {
    const int src = csr_src[beg + i];
    float s = ssrc[src * 4 + head] + sd;
    s = s > 0.f ? s : NEG_SLOPE * s;
    if (i == lane) s_keep = s;               // edge beg+lane (for deg<=32 fast path)
    const float mn = fmaxf(m, s);
    l = l * __expf(m - mn) + __expf(s - mn);
    m = mn;
  }
  // merge across the 32-lane head group (guard -inf/-inf -> NaN)
  #pragma unroll
  for (int off = 16; off; off >>= 1) {
    const float m2 = __shfl_xor(m, off, 32);
    const float l2 = __shfl_xor(l, off, 32);
    const float mn = fmaxf(m, m2);
    if (mn == -INFINITY) { m = -INFINITY; l = 0.f; }
    else {
      l = l * __expf(m - mn) + l2 * __expf(m2 - mn);
      m = mn;
    }
  }
  const float inv_l = 1.f / l;               // unused when deg==0

  // Phase B: weighted gather-sum; prefetch next src to hide latency
  float acc = 0.f;
  const bool small = (deg <= 32);
  int src_next = (deg > 0) ? csr_src[beg] : 0;
  for (int i = 0; i < deg; ++i) {
    const int src = src_next;
    if (i + 1 < deg) src_next = csr_src[beg + i + 1];
    float s;
    if (small) {
      s = __shfl(s_keep, i, 32);             // broadcast stashed s from lane i
    } else {
      float sv = ssrc[src * 4 + head] + sd;
      s = sv > 0.f ? sv : NEG_SLOPE * sv;
    }
    const float alpha = __expf(s - m) * inv_l;
    acc = fmaf(alpha, h[(size_t)src * 128 + t], acc);
  }

  // residual + LayerNorm + ELU
  const float r = acc + x[(size_t)node * 128 + t];
  float s1 = r, s2 = r * r;
  #pragma unroll
  for (int off = 32; off; off >>= 1) {       // full wave64 butterfly
    s1 += __shfl_xor(s1, off, 64);
    s2 += __shfl_xor(s2, off, 64);
  }
  __shared__ float red[4];
  if ((t & 63) == 0) { red[(t >> 6) * 2] = s1; red[(t >> 6) * 2 + 1] = s2; }
  __syncthreads();
  const float tot1 = red[0] + red[2];
  const float tot2 = red[1] + red[3];
  const float mu   = tot1 * (1.f / 128.f);
  const float var  = tot2 * (1.f / 128.f) - mu * mu;
  const float rstd = rsqrtf(var + LN_EPS);
  const float o = (r - mu) * rstd * gamma[t] + beta[t];
  out[(size_t)node * 128 + t] = o > 0.f ? o : expm1f(o);
}

// ---------------------------------------------------------------------------
extern "C" void kernel_launch(void* const* d_in, const int* in_sizes, int n_in,
                              void* d_out, int out_size, void* d_ws, size_t ws_size,
                              hipStream_t stream)
{
  const float* x    = (const float*)d_in[0];
  const int*   ei   = (const int*)d_in[1];
  const float* W    = (const float*)d_in[2];
  const float* a_s  = (const float*)d_in[3];
  const float* a_d  = (const float*)d_in[4];
  const float* gam  = (const float*)d_in[5];
  const float* bet  = (const float*)d_in[6];
  float* out = (float*)d_out;

  const int n_nodes = in_sizes[0] / 128;
  const int n_edges = in_sizes[1] / 2;
  const int* e_src = ei;
  const int* e_dst = ei + n_edges;

  // workspace carve-up (~60 MB)
  char* p = (char*)d_ws;
  float* h    = (float*)p;  p += (size_t)n_nodes * 128 * sizeof(float);
  float* ssrc = (float*)p;  p += (size_t)n_nodes * 4 * sizeof(float);
  float* sdst = (float*)p;  p += (size_t)n_nodes * 4 * sizeof(float);
  int* counts    = (int*)p; p += (size_t)n_nodes * sizeof(int);
  int* row_start = (int*)p; p += (size_t)(n_nodes + 4) * sizeof(int);
  int* blk_sums  = (int*)p; p += 128 * sizeof(int);
  int* cursor    = (int*)p; p += (size_t)n_nodes * sizeof(int);
  int* csr_src   = (int*)p; p += (size_t)n_edges * sizeof(int);

  hipMemsetAsync(counts, 0, (size_t)n_nodes * sizeof(int), stream);

  k_proj<<<(n_nodes + 31) / 32, 256, 0, stream>>>(x, W, a_s, a_d, h, ssrc, sdst, n_nodes);
  k_count<<<(n_edges + 255) / 256, 256, 0, stream>>>(e_dst, counts, n_edges);
  const int nblk = (n_nodes + 1023) / 1024;
  k_scan1<<<nblk, 256, 0, stream>>>(counts, row_start, blk_sums, n_nodes);
  k_scan2<<<1, 128, 0, stream>>>(blk_sums, nblk, row_start, n_nodes, n_edges);
  k_scan3<<<nblk, 256, 0, stream>>>(row_start, blk_sums, cursor, n_nodes);
  k_fill<<<(n_edges + 255) / 256, 256, 0, stream>>>(e_src, e_dst, cursor, csr_src, n_edges);
  k_agg<<<n_nodes, 128, 0, stream>>>(h, ssrc, sdst, row_start, csr_src, x, gam, bet, out);
}

// Round 2
// 331.563 us; speedup vs baseline: 1.1850x; 1.1850x over previous
//
#include <hip/hip_runtime.h>
#include <math.h>

#define NEG_SLOPE 0.2f
#define LN_EPS 1e-5f

// ---------------------------------------------------------------------------
// k_proj: h = x @ W  ([N,128]x[128,128]), fused per-node attention scalars.
// Block = 256 threads: c = t&31 (4 cols each), rg = t>>5 (4 rows each)
// -> 32 rows x 128 cols per block. W staged in LDS in four 32-row quarters
// (16 KB) + transposed x tile (18 KB) => ~34 KB LDS -> 4 blocks/CU.
// Inner loop: 2x ds_read_b128 -> 16 FMA (VALU-bound by design).
// ---------------------------------------------------------------------------
__global__ __launch_bounds__(256) void k_proj(
    const float* __restrict__ x, const float* __restrict__ W,
    const float* __restrict__ a_src, const float* __restrict__ a_dst,
    float* __restrict__ h, float* __restrict__ ssrc, float* __restrict__ sdst,
    int n_nodes)
{
  __shared__ __align__(16) float wlds[32 * 128];   // one k-quarter of W
  __shared__ __align__(16) float xt[128 * 36];     // x transposed [k][row], stride 36
  const int t  = threadIdx.x;
  const int c  = t & 31;      // col group: cols 4c..4c+3
  const int rg = t >> 5;      // row group: rows rg*4..rg*4+3
  const int base = blockIdx.x * 32;

  const int dl = (c & 7) * 4;
  const float as0 = a_src[dl+0], as1 = a_src[dl+1], as2 = a_src[dl+2], as3 = a_src[dl+3];
  const float ad0 = a_dst[dl+0], ad1 = a_dst[dl+1], ad2 = a_dst[dl+2], ad3 = a_dst[dl+3];

  // stage x tile transposed: xt[k][row_local]
  for (int ii = t * 4; ii < 32 * 128; ii += 1024) {
    const int rl = ii >> 7;
    const int k0 = ii & 127;
    const int grow = base + rl;
    float4 v = make_float4(0.f, 0.f, 0.f, 0.f);
    if (grow < n_nodes) v = *(const float4*)(x + (size_t)grow * 128 + k0);
    xt[(k0+0)*36 + rl] = v.x;
    xt[(k0+1)*36 + rl] = v.y;
    xt[(k0+2)*36 + rl] = v.z;
    xt[(k0+3)*36 + rl] = v.w;
  }

  float acc[4][4] = {};
  for (int quar = 0; quar < 4; ++quar) {
    __syncthreads();                       // protect wlds from previous quarter
    for (int i = t * 4; i < 32 * 128; i += 1024)
      *(float4*)(wlds + i) = *(const float4*)(W + quar * 32 * 128 + i);
    __syncthreads();
    #pragma unroll 8
    for (int k2 = 0; k2 < 32; ++k2) {
      const int k = quar * 32 + k2;
      const float4 wv = *(const float4*)(&wlds[k2 * 128 + 4 * c]);
      const float4 xv = *(const float4*)(&xt[k * 36 + rg * 4]);
      acc[0][0] = fmaf(xv.x, wv.x, acc[0][0]);
      acc[0][1] = fmaf(xv.x, wv.y, acc[0][1]);
      acc[0][2] = fmaf(xv.x, wv.z, acc[0][2]);
      acc[0][3] = fmaf(xv.x, wv.w, acc[0][3]);
      acc[1][0] = fmaf(xv.y, wv.x, acc[1][0]);
      acc[1][1] = fmaf(xv.y, wv.y, acc[1][1]);
      acc[1][2] = fmaf(xv.y, wv.z, acc[1][2]);
      acc[1][3] = fmaf(xv.y, wv.w, acc[1][3]);
      acc[2][0] = fmaf(xv.z, wv.x, acc[2][0]);
      acc[2][1] = fmaf(xv.z, wv.y, acc[2][1]);
      acc[2][2] = fmaf(xv.z, wv.z, acc[2][2]);
      acc[2][3] = fmaf(xv.z, wv.w, acc[2][3]);
      acc[3][0] = fmaf(xv.w, wv.x, acc[3][0]);
      acc[3][1] = fmaf(xv.w, wv.y, acc[3][1]);
      acc[3][2] = fmaf(xv.w, wv.z, acc[3][2]);
      acc[3][3] = fmaf(xv.w, wv.w, acc[3][3]);
    }
  }

  // epilogue: store h, reduce attention scalars across 8-lane col groups
  #pragma unroll
  for (int rr = 0; rr < 4; ++rr) {
    const int row = base + rg * 4 + rr;
    if (row < n_nodes)
      *(float4*)(h + (size_t)row * 128 + 4 * c) =
          make_float4(acc[rr][0], acc[rr][1], acc[rr][2], acc[rr][3]);
    float ps = acc[rr][0]*as0 + acc[rr][1]*as1 + acc[rr][2]*as2 + acc[rr][3]*as3;
    float pd = acc[rr][0]*ad0 + acc[rr][1]*ad1 + acc[rr][2]*ad2 + acc[rr][3]*ad3;
    #pragma unroll
    for (int off = 1; off < 8; off <<= 1) {
      ps += __shfl_xor(ps, off, 8);
      pd += __shfl_xor(pd, off, 8);
    }
    if ((c & 7) == 0 && row < n_nodes) {
      const int head = c >> 3;
      ssrc[row * 4 + head] = ps;
      sdst[row * 4 + head] = pd;
    }
  }
}

// ---------------------------------------------------------------------------
// CSR build: count -> 3-kernel exclusive scan -> fill (stores src node id)
// ---------------------------------------------------------------------------
__global__ void k_count(const int* __restrict__ dst, int* __restrict__ counts, int n_edges) {
  int e = (blockIdx.x * 256 + threadIdx.x) * 4;
  if (e + 4 <= n_edges) {
    const int4 d = *(const int4*)(dst + e);
    atomicAdd(&counts[d.x], 1);
    atomicAdd(&counts[d.y], 1);
    atomicAdd(&counts[d.z], 1);
    atomicAdd(&counts[d.w], 1);
  } else {
    for (; e < n_edges; ++e) atomicAdd(&counts[dst[e]], 1);
  }
}

__global__ __launch_bounds__(256) void k_scan1(const int* __restrict__ counts,
    int* __restrict__ row_start, int* __restrict__ blk_sums, int n) {
  __shared__ int sdata[256];
  const int t = threadIdx.x;
  const int base = blockIdx.x * 1024 + t * 4;
  const int v0 = (base+0 < n) ? counts[base+0] : 0;
  const int v1 = (base+1 < n) ? counts[base+1] : 0;
  const int v2 = (base+2 < n) ? counts[base+2] : 0;
  const int v3 = (base+3 < n) ? counts[base+3] : 0;
  const int tsum = v0 + v1 + v2 + v3;
  sdata[t] = tsum;
  __syncthreads();
  for (int off = 1; off < 256; off <<= 1) {
    const int addv = (t >= off) ? sdata[t - off] : 0;
    __syncthreads();
    sdata[t] += addv;
    __syncthreads();
  }
  int excl = sdata[t] - tsum;
  if (base+0 < n) row_start[base+0] = excl;  excl += v0;
  if (base+1 < n) row_start[base+1] = excl;  excl += v1;
  if (base+2 < n) row_start[base+2] = excl;  excl += v2;
  if (base+3 < n) row_start[base+3] = excl;
  if (t == 255) blk_sums[blockIdx.x] = sdata[255];
}

__global__ __launch_bounds__(128) void k_scan2(int* __restrict__ blk_sums, int nblk,
    int* __restrict__ row_start, int n, int n_edges) {
  __shared__ int sd[128];
  const int t = threadIdx.x;
  const int v = (t < nblk) ? blk_sums[t] : 0;
  sd[t] = v;
  __syncthreads();
  for (int off = 1; off < 128; off <<= 1) {
    const int addv = (t >= off) ? sd[t - off] : 0;
    __syncthreads();
    sd[t] += addv;
    __syncthreads();
  }
  if (t < nblk) blk_sums[t] = sd[t] - v;   // exclusive block offsets
  if (t == 0) row_start[n] = n_edges;
}

__global__ __launch_bounds__(256) void k_scan3(int* __restrict__ row_start,
    const int* __restrict__ blk_sums, int* __restrict__ cursor, int n) {
  const int off = blk_sums[blockIdx.x];
  const int base = blockIdx.x * 1024 + threadIdx.x * 4;
  #pragma unroll
  for (int j = 0; j < 4; ++j) {
    const int i = base + j;
    if (i < n) {
      const int vfin = row_start[i] + off;
      row_start[i] = vfin;
      cursor[i] = vfin;
    }
  }
}

__global__ void k_fill(const int* __restrict__ src, const int* __restrict__ dst,
                       int* __restrict__ cursor, int* __restrict__ csr_src, int n_edges) {
  int e = (blockIdx.x * 256 + threadIdx.x) * 4;
  if (e + 4 <= n_edges) {
    const int4 s = *(const int4*)(src + e);
    const int4 d = *(const int4*)(dst + e);
    csr_src[atomicAdd(&cursor[d.x], 1)] = s.x;
    csr_src[atomicAdd(&cursor[d.y], 1)] = s.y;
    csr_src[atomicAdd(&cursor[d.z], 1)] = s.z;
    csr_src[atomicAdd(&cursor[d.w], 1)] = s.w;
  } else {
    for (; e < n_edges; ++e)
      csr_src[atomicAdd(&cursor[dst[e]], 1)] = src[e];
  }
}

// ---------------------------------------------------------------------------
// k_agg v2: 32 lanes per node (one wave = 2 nodes; block 256 = 8 nodes).
// Lane q in [0,32): owns float4 at d = 4q; head = q>>3.
// Phase A: 8-lane head groups do online softmax stats over strided edges,
//          stashing s for edges 0..15 in registers; shfl-merge (xor 1,2,4).
// Phase B: unroll-2 alpha-weighted float4 gather of h[src] (2 loads in
//          flight). deg>16 (rare, ~0.4%) recomputes s from ssrc.
// Epilogue: residual + LayerNorm (32-lane shfl reduce) + ELU. No LDS/atomics.
// ---------------------------------------------------------------------------
__global__ __launch_bounds__(256) void k_agg(
    const float* __restrict__ h, const float* __restrict__ ssrc,
    const float* __restrict__ sdst, const int* __restrict__ row_start,
    const int* __restrict__ csr_src, const float* __restrict__ x,
    const float* __restrict__ gamma, const float* __restrict__ beta,
    float* __restrict__ out, int n_nodes)
{
  const int t    = threadIdx.x;
  const int lane = t & 63;
  const int q    = lane & 31;
  const int node = blockIdx.x * 8 + (t >> 6) * 2 + (lane >> 5);
  if (node >= n_nodes) return;           // uniform per 32-lane half
  const int head = q >> 3;
  const int beg  = row_start[node];
  const int deg  = row_start[node + 1] - beg;
  const float sd = sdst[node * 4 + head];

  // Phase A: online max/sum over strided edge subset (8 lanes per head)
  float m = -INFINITY, l = 0.f;
  float sk0 = 0.f, sk1 = 0.f;            // stash: s for edges (q&7), (q&7)+8
  for (int i = (q & 7); i < deg; i += 8) {
    const int src = csr_src[beg + i];
    float s = ssrc[src * 4 + head] + sd;
    s = s > 0.f ? s : NEG_SLOPE * s;
    if (i < 8) sk0 = s; else if (i < 16) sk1 = s;
    const float mn = fmaxf(m, s);
    l = l * __expf(m - mn) + __expf(s - mn);
    m = mn;
  }
  #pragma unroll
  for (int off = 1; off < 8; off <<= 1) {   // merge within 8-lane head group
    const float m2 = __shfl_xor(m, off);
    const float l2 = __shfl_xor(l, off);
    const float mn = fmaxf(m, m2);
    if (mn == -INFINITY) { m = -INFINITY; l = 0.f; }
    else {
      l = l * __expf(m - mn) + l2 * __expf(m2 - mn);
      m = mn;
    }
  }
  const float inv_l = (deg > 0) ? 1.f / l : 0.f;
  const int  sbase  = lane & 56;         // sub*32 + (q&24): stash lane base
  const bool small  = (deg <= 16);

  // Phase B: unrolled weighted float4 gather
  float4 acc0 = make_float4(0.f, 0.f, 0.f, 0.f);
  float4 acc1 = make_float4(0.f, 0.f, 0.f, 0.f);
  int i = 0;
  for (; i + 2 <= deg; i += 2) {
    const int srcA = csr_src[beg + i];
    const int srcB = csr_src[beg + i + 1];
    float sA, sB;
    if (small) {
      const float svA = (i & 8) ? sk1 : sk0;
      const float svB = ((i + 1) & 8) ? sk1 : sk0;
      sA = __shfl(svA, sbase | (i & 7));
      sB = __shfl(svB, sbase | ((i + 1) & 7));
    } else {
      float a = ssrc[srcA * 4 + head] + sd; sA = a > 0.f ? a : NEG_SLOPE * a;
      float b = ssrc[srcB * 4 + head] + sd; sB = b > 0.f ? b : NEG_SLOPE * b;
    }
    const float alA = __expf(sA - m) * inv_l;
    const float alB = __expf(sB - m) * inv_l;
    const float4 hA = *(const float4*)(h + (size_t)srcA * 128 + q * 4);
    const float4 hB = *(const float4*)(h + (size_t)srcB * 128 + q * 4);
    acc0.x = fmaf(alA, hA.x, acc0.x);
    acc0.y = fmaf(alA, hA.y, acc0.y);
    acc0.z = fmaf(alA, hA.z, acc0.z);
    acc0.w = fmaf(alA, hA.w, acc0.w);
    acc1.x = fmaf(alB, hB.x, acc1.x);
    acc1.y = fmaf(alB, hB.y, acc1.y);
    acc1.z = fmaf(alB, hB.z, acc1.z);
    acc1.w = fmaf(alB, hB.w, acc1.w);
  }
  if (i < deg) {                          // tail edge
    const int srcA = csr_src[beg + i];
    float sA;
    if (small) {
      const float svA = (i & 8) ? sk1 : sk0;
      sA = __shfl(svA, sbase | (i & 7));
    } else {
      float a = ssrc[srcA * 4 + head] + sd; sA = a > 0.f ? a : NEG_SLOPE * a;
    }
    const float alA = __expf(sA - m) * inv_l;
    const float4 hA = *(const float4*)(h + (size_t)srcA * 128 + q * 4);
    acc0.x = fmaf(alA, hA.x, acc0.x);
    acc0.y = fmaf(alA, hA.y, acc0.y);
    acc0.z = fmaf(alA, hA.z, acc0.z);
    acc0.w = fmaf(alA, hA.w, acc0.w);
  }

  // residual + LayerNorm + ELU (all within the 32-lane node group)
  const float4 xv = *(const float4*)(x + (size_t)node * 128 + q * 4);
  float4 r;
  r.x = acc0.x + acc1.x + xv.x;
  r.y = acc0.y + acc1.y + xv.y;
  r.z = acc0.z + acc1.z + xv.z;
  r.w = acc0.w + acc1.w + xv.w;
  float s1 = r.x + r.y + r.z + r.w;
  float s2 = r.x*r.x + r.y*r.y + r.z*r.z + r.w*r.w;
  #pragma unroll
  for (int off = 16; off; off >>= 1) {    // xor masks stay within the 32-half
    s1 += __shfl_xor(s1, off);
    s2 += __shfl_xor(s2, off);
  }
  const float mu   = s1 * (1.f / 128.f);
  const float var  = s2 * (1.f / 128.f) - mu * mu;
  const float rstd = rsqrtf(var + LN_EPS);
  const float4 g4 = *(const float4*)(gamma + q * 4);
  const float4 b4 = *(const float4*)(beta  + q * 4);
  float4 o;
  o.x = (r.x - mu) * rstd * g4.x + b4.x;
  o.y = (r.y - mu) * rstd * g4.y + b4.y;
  o.z = (r.z - mu) * rstd * g4.z + b4.z;
  o.w = (r.w - mu) * rstd * g4.w + b4.w;
  o.x = o.x > 0.f ? o.x : expm1f(o.x);
  o.y = o.y > 0.f ? o.y : expm1f(o.y);
  o.z = o.z > 0.f ? o.z : expm1f(o.z);
  o.w = o.w > 0.f ? o.w : expm1f(o.w);
  *(float4*)(out + (size_t)node * 128 + q * 4) = o;
}

// ---------------------------------------------------------------------------
extern "C" void kernel_launch(void* const* d_in, const int* in_sizes, int n_in,
                              void* d_out, int out_size, void* d_ws, size_t ws_size,
                              hipStream_t stream)
{
  const float* x    = (const float*)d_in[0];
  const int*   ei   = (const int*)d_in[1];
  const float* W    = (const float*)d_in[2];
  const float* a_s  = (const float*)d_in[3];
  const float* a_d  = (const float*)d_in[4];
  const float* gam  = (const float*)d_in[5];
  const float* bet  = (const float*)d_in[6];
  float* out = (float*)d_out;

  const int n_nodes = in_sizes[0] / 128;
  const int n_edges = in_sizes[1] / 2;
  const int* e_src = ei;
  const int* e_dst = ei + n_edges;

  // workspace carve-up (~60 MB)
  char* p = (char*)d_ws;
  float* h    = (float*)p;  p += (size_t)n_nodes * 128 * sizeof(float);
  float* ssrc = (float*)p;  p += (size_t)n_nodes * 4 * sizeof(float);
  float* sdst = (float*)p;  p += (size_t)n_nodes * 4 * sizeof(float);
  int* counts    = (int*)p; p += (size_t)n_nodes * sizeof(int);
  int* row_start = (int*)p; p += (size_t)(n_nodes + 4) * sizeof(int);
  int* blk_sums  = (int*)p; p += 128 * sizeof(int);
  int* cursor    = (int*)p; p += (size_t)n_nodes * sizeof(int);
  int* csr_src   = (int*)p; p += (size_t)n_edges * sizeof(int);

  hipMemsetAsync(counts, 0, (size_t)n_nodes * sizeof(int), stream);

  k_proj<<<(n_nodes + 31) / 32, 256, 0, stream>>>(x, W, a_s, a_d, h, ssrc, sdst, n_nodes);
  k_count<<<(n_edges + 1023) / 1024, 256, 0, stream>>>(e_dst, counts, n_edges);
  const int nblk = (n_nodes + 1023) / 1024;
  k_scan1<<<nblk, 256, 0, stream>>>(counts, row_start, blk_sums, n_nodes);
  k_scan2<<<1, 128, 0, stream>>>(blk_sums, nblk, row_start, n_nodes, n_edges);
  k_scan3<<<nblk, 256, 0, stream>>>(row_start, blk_sums, cursor, n_nodes);
  k_fill<<<(n_edges + 1023) / 1024, 256, 0, stream>>>(e_src, e_dst, cursor, csr_src, n_edges);
  k_agg<<<(n_nodes + 7) / 8, 256, 0, stream>>>(h, ssrc, sdst, row_start, csr_src, x, gam, bet, out, n_nodes);
}

// Round 3
// 290.847 us; speedup vs baseline: 1.3509x; 1.1400x over previous
//
#include <hip/hip_runtime.h>
#include <math.h>

#define NEG_SLOPE 0.2f
#define LN_EPS 1e-5f

// pack two fp32 into bf16x2 (RTNE), elem0 in low half
static __device__ __forceinline__ unsigned pack_bf16(float a, float b) {
  unsigned ua = __float_as_uint(a);
  unsigned ub = __float_as_uint(b);
  ua += 0x7fffu + ((ua >> 16) & 1u);
  ub += 0x7fffu + ((ub >> 16) & 1u);
  return (ua >> 16) | (ub & 0xffff0000u);
}
static __device__ __forceinline__ float bf_lo(unsigned u) { return __uint_as_float(u << 16); }
static __device__ __forceinline__ float bf_hi(unsigned u) { return __uint_as_float(u & 0xffff0000u); }

// ---------------------------------------------------------------------------
// k_proj_count: block-role fusion.
//  Blocks [0, nproj): h = x @ W (h stored as packed bf16), fused per-node
//    attention scalars ssrc/sdst (computed from fp32 accumulators).
//  Blocks [nproj, ...): degree counting (atomicAdd on counts[dst]) — atomic-
//    latency-bound work that co-schedules under the VALU-bound proj blocks.
// Proj tile: 32 rows x 128 cols per 256-thread block; W staged in LDS in
// four 32-row quarters (16 KB) + transposed x tile (18 KB) -> ~34 KB LDS.
// ---------------------------------------------------------------------------
__global__ __launch_bounds__(256) void k_proj_count(
    const float* __restrict__ x, const float* __restrict__ W,
    const float* __restrict__ a_src, const float* __restrict__ a_dst,
    unsigned* __restrict__ h, float* __restrict__ ssrc, float* __restrict__ sdst,
    int n_nodes, const int* __restrict__ e_dst, int* __restrict__ counts,
    int n_edges, int nproj)
{
  __shared__ __align__(16) float wlds[32 * 128];   // one k-quarter of W
  __shared__ __align__(16) float xt[128 * 36];     // x transposed [k][row], stride 36

  if (blockIdx.x >= nproj) {
    // ---- count role: 4 edges per thread via int4 (fire-and-forget atomics)
    int e = ((blockIdx.x - nproj) * 256 + threadIdx.x) * 4;
    if (e + 4 <= n_edges) {
      const int4 d = *(const int4*)(e_dst + e);
      atomicAdd(&counts[d.x], 1);
      atomicAdd(&counts[d.y], 1);
      atomicAdd(&counts[d.z], 1);
      atomicAdd(&counts[d.w], 1);
    } else {
      for (; e < n_edges; ++e) atomicAdd(&counts[e_dst[e]], 1);
    }
    return;
  }

  const int t  = threadIdx.x;
  const int c  = t & 31;      // col group: cols 4c..4c+3
  const int rg = t >> 5;      // row group: rows rg*4..rg*4+3
  const int base = blockIdx.x * 32;

  const int dl = (c & 7) * 4;
  const float as0 = a_src[dl+0], as1 = a_src[dl+1], as2 = a_src[dl+2], as3 = a_src[dl+3];
  const float ad0 = a_dst[dl+0], ad1 = a_dst[dl+1], ad2 = a_dst[dl+2], ad3 = a_dst[dl+3];

  // stage x tile transposed: xt[k][row_local]
  for (int ii = t * 4; ii < 32 * 128; ii += 1024) {
    const int rl = ii >> 7;
    const int k0 = ii & 127;
    const int grow = base + rl;
    float4 v = make_float4(0.f, 0.f, 0.f, 0.f);
    if (grow < n_nodes) v = *(const float4*)(x + (size_t)grow * 128 + k0);
    xt[(k0+0)*36 + rl] = v.x;
    xt[(k0+1)*36 + rl] = v.y;
    xt[(k0+2)*36 + rl] = v.z;
    xt[(k0+3)*36 + rl] = v.w;
  }

  float acc[4][4] = {};
  for (int quar = 0; quar < 4; ++quar) {
    __syncthreads();                       // protect wlds from previous quarter
    for (int i = t * 4; i < 32 * 128; i += 1024)
      *(float4*)(wlds + i) = *(const float4*)(W + quar * 32 * 128 + i);
    __syncthreads();
    #pragma unroll 8
    for (int k2 = 0; k2 < 32; ++k2) {
      const int k = quar * 32 + k2;
      const float4 wv = *(const float4*)(&wlds[k2 * 128 + 4 * c]);
      const float4 xv = *(const float4*)(&xt[k * 36 + rg * 4]);
      acc[0][0] = fmaf(xv.x, wv.x, acc[0][0]);
      acc[0][1] = fmaf(xv.x, wv.y, acc[0][1]);
      acc[0][2] = fmaf(xv.x, wv.z, acc[0][2]);
      acc[0][3] = fmaf(xv.x, wv.w, acc[0][3]);
      acc[1][0] = fmaf(xv.y, wv.x, acc[1][0]);
      acc[1][1] = fmaf(xv.y, wv.y, acc[1][1]);
      acc[1][2] = fmaf(xv.y, wv.z, acc[1][2]);
      acc[1][3] = fmaf(xv.y, wv.w, acc[1][3]);
      acc[2][0] = fmaf(xv.z, wv.x, acc[2][0]);
      acc[2][1] = fmaf(xv.z, wv.y, acc[2][1]);
      acc[2][2] = fmaf(xv.z, wv.z, acc[2][2]);
      acc[2][3] = fmaf(xv.z, wv.w, acc[2][3]);
      acc[3][0] = fmaf(xv.w, wv.x, acc[3][0]);
      acc[3][1] = fmaf(xv.w, wv.y, acc[3][1]);
      acc[3][2] = fmaf(xv.w, wv.z, acc[3][2]);
      acc[3][3] = fmaf(xv.w, wv.w, acc[3][3]);
    }
  }

  // epilogue: store h (bf16-packed), reduce attention scalars (fp32 accs)
  #pragma unroll
  for (int rr = 0; rr < 4; ++rr) {
    const int row = base + rg * 4 + rr;
    if (row < n_nodes) {
      uint2 p;
      p.x = pack_bf16(acc[rr][0], acc[rr][1]);
      p.y = pack_bf16(acc[rr][2], acc[rr][3]);
      *(uint2*)(h + (size_t)row * 64 + 2 * c) = p;
    }
    float ps = acc[rr][0]*as0 + acc[rr][1]*as1 + acc[rr][2]*as2 + acc[rr][3]*as3;
    float pd = acc[rr][0]*ad0 + acc[rr][1]*ad1 + acc[rr][2]*ad2 + acc[rr][3]*ad3;
    #pragma unroll
    for (int off = 1; off < 8; off <<= 1) {
      ps += __shfl_xor(ps, off, 8);
      pd += __shfl_xor(pd, off, 8);
    }
    if ((c & 7) == 0 && row < n_nodes) {
      const int head = c >> 3;
      ssrc[row * 4 + head] = ps;
      sdst[row * 4 + head] = pd;
    }
  }
}

// ---------------------------------------------------------------------------
// CSR build: 3-kernel exclusive scan -> fill (stores src node id)
// ---------------------------------------------------------------------------
__global__ __launch_bounds__(256) void k_scan1(const int* __restrict__ counts,
    int* __restrict__ row_start, int* __restrict__ blk_sums, int n) {
  __shared__ int sdata[256];
  const int t = threadIdx.x;
  const int base = blockIdx.x * 1024 + t * 4;
  const int v0 = (base+0 < n) ? counts[base+0] : 0;
  const int v1 = (base+1 < n) ? counts[base+1] : 0;
  const int v2 = (base+2 < n) ? counts[base+2] : 0;
  const int v3 = (base+3 < n) ? counts[base+3] : 0;
  const int tsum = v0 + v1 + v2 + v3;
  sdata[t] = tsum;
  __syncthreads();
  for (int off = 1; off < 256; off <<= 1) {
    const int addv = (t >= off) ? sdata[t - off] : 0;
    __syncthreads();
    sdata[t] += addv;
    __syncthreads();
  }
  int excl = sdata[t] - tsum;
  if (base+0 < n) row_start[base+0] = excl;  excl += v0;
  if (base+1 < n) row_start[base+1] = excl;  excl += v1;
  if (base+2 < n) row_start[base+2] = excl;  excl += v2;
  if (base+3 < n) row_start[base+3] = excl;
  if (t == 255) blk_sums[blockIdx.x] = sdata[255];
}

__global__ __launch_bounds__(128) void k_scan2(int* __restrict__ blk_sums, int nblk,
    int* __restrict__ row_start, int n, int n_edges) {
  __shared__ int sd[128];
  const int t = threadIdx.x;
  const int v = (t < nblk) ? blk_sums[t] : 0;
  sd[t] = v;
  __syncthreads();
  for (int off = 1; off < 128; off <<= 1) {
    const int addv = (t >= off) ? sd[t - off] : 0;
    __syncthreads();
    sd[t] += addv;
    __syncthreads();
  }
  if (t < nblk) blk_sums[t] = sd[t] - v;   // exclusive block offsets
  if (t == 0) row_start[n] = n_edges;
}

__global__ __launch_bounds__(256) void k_scan3(int* __restrict__ row_start,
    const int* __restrict__ blk_sums, int* __restrict__ cursor, int n) {
  const int off = blk_sums[blockIdx.x];
  const int base = blockIdx.x * 1024 + threadIdx.x * 4;
  #pragma unroll
  for (int j = 0; j < 4; ++j) {
    const int i = base + j;
    if (i < n) {
      const int vfin = row_start[i] + off;
      row_start[i] = vfin;
      cursor[i] = vfin;
    }
  }
}

// 1 edge/thread: returning atomics need TLP, not per-thread unrolling
__global__ void k_fill(const int* __restrict__ src, const int* __restrict__ dst,
                       int* __restrict__ cursor, int* __restrict__ csr_src, int n_edges) {
  const int e = blockIdx.x * 256 + threadIdx.x;
  if (e < n_edges) {
    const int pos = atomicAdd(&cursor[dst[e]], 1);
    csr_src[pos] = src[e];
  }
}

// ---------------------------------------------------------------------------
// k_agg: 32 lanes per node (block 256 = 8 nodes). Lane q owns d = 4q..4q+3.
// Phase A: 8-lane head groups, online softmax stats; s stashed for edges
//          0..15 (covers deg<=16, ~99.6% of Poisson(8) nodes).
// Phase B: unroll-2 alpha-weighted gather of bf16-packed h (dwordx2/lane).
// Epilogue: residual + LayerNorm (32-lane shfl) + ELU. No LDS/atomics.
// ---------------------------------------------------------------------------
__global__ __launch_bounds__(256) void k_agg(
    const unsigned* __restrict__ h, const float* __restrict__ ssrc,
    const float* __restrict__ sdst, const int* __restrict__ row_start,
    const int* __restrict__ csr_src, const float* __restrict__ x,
    const float* __restrict__ gamma, const float* __restrict__ beta,
    float* __restrict__ out, int n_nodes)
{
  const int t    = threadIdx.x;
  const int lane = t & 63;
  const int q    = lane & 31;
  const int node = blockIdx.x * 8 + (t >> 6) * 2 + (lane >> 5);
  if (node >= n_nodes) return;           // uniform per 32-lane half
  const int head = q >> 3;
  const int beg  = row_start[node];
  const int deg  = row_start[node + 1] - beg;
  const float sd = sdst[node * 4 + head];

  // Phase A: online max/sum over strided edge subset (8 lanes per head)
  float m = -INFINITY, l = 0.f;
  float sk0 = 0.f, sk1 = 0.f;            // stash: s for edges (q&7), (q&7)+8
  for (int i = (q & 7); i < deg; i += 8) {
    const int src = csr_src[beg + i];
    float s = ssrc[src * 4 + head] + sd;
    s = s > 0.f ? s : NEG_SLOPE * s;
    if (i < 8) sk0 = s; else if (i < 16) sk1 = s;
    const float mn = fmaxf(m, s);
    l = l * __expf(m - mn) + __expf(s - mn);
    m = mn;
  }
  #pragma unroll
  for (int off = 1; off < 8; off <<= 1) {   // merge within 8-lane head group
    const float m2 = __shfl_xor(m, off);
    const float l2 = __shfl_xor(l, off);
    const float mn = fmaxf(m, m2);
    if (mn == -INFINITY) { m = -INFINITY; l = 0.f; }
    else {
      l = l * __expf(m - mn) + l2 * __expf(m2 - mn);
      m = mn;
    }
  }
  const float inv_l = (deg > 0) ? 1.f / l : 0.f;
  const int  sbase  = lane & 56;         // 32-half base | (q&24)
  const bool small  = (deg <= 16);

  // Phase B: unrolled weighted bf16 gather (uint2 = 4 bf16 per lane)
  float4 acc0 = make_float4(0.f, 0.f, 0.f, 0.f);
  float4 acc1 = make_float4(0.f, 0.f, 0.f, 0.f);
  int i = 0;
  for (; i + 2 <= deg; i += 2) {
    const int srcA = csr_src[beg + i];
    const int srcB = csr_src[beg + i + 1];
    const uint2 hA = *(const uint2*)(h + (size_t)srcA * 64 + q * 2);
    const uint2 hB = *(const uint2*)(h + (size_t)srcB * 64 + q * 2);
    float sA, sB;
    if (small) {
      const float svA = (i & 8) ? sk1 : sk0;
      const float svB = ((i + 1) & 8) ? sk1 : sk0;
      sA = __shfl(svA, sbase | (i & 7));
      sB = __shfl(svB, sbase | ((i + 1) & 7));
    } else {
      float a = ssrc[srcA * 4 + head] + sd; sA = a > 0.f ? a : NEG_SLOPE * a;
      float b = ssrc[srcB * 4 + head] + sd; sB = b > 0.f ? b : NEG_SLOPE * b;
    }
    const float alA = __expf(sA - m) * inv_l;
    const float alB = __expf(sB - m) * inv_l;
    acc0.x = fmaf(alA, bf_lo(hA.x), acc0.x);
    acc0.y = fmaf(alA, bf_hi(hA.x), acc0.y);
    acc0.z = fmaf(alA, bf_lo(hA.y), acc0.z);
    acc0.w = fmaf(alA, bf_hi(hA.y), acc0.w);
    acc1.x = fmaf(alB, bf_lo(hB.x), acc1.x);
    acc1.y = fmaf(alB, bf_hi(hB.x), acc1.y);
    acc1.z = fmaf(alB, bf_lo(hB.y), acc1.z);
    acc1.w = fmaf(alB, bf_hi(hB.y), acc1.w);
  }
  if (i < deg) {                          // tail edge
    const int srcA = csr_src[beg + i];
    const uint2 hA = *(const uint2*)(h + (size_t)srcA * 64 + q * 2);
    float sA;
    if (small) {
      const float svA = (i & 8) ? sk1 : sk0;
      sA = __shfl(svA, sbase | (i & 7));
    } else {
      float a = ssrc[srcA * 4 + head] + sd; sA = a > 0.f ? a : NEG_SLOPE * a;
    }
    const float alA = __expf(sA - m) * inv_l;
    acc0.x = fmaf(alA, bf_lo(hA.x), acc0.x);
    acc0.y = fmaf(alA, bf_hi(hA.x), acc0.y);
    acc0.z = fmaf(alA, bf_lo(hA.y), acc0.z);
    acc0.w = fmaf(alA, bf_hi(hA.y), acc0.w);
  }

  // residual + LayerNorm + ELU (all within the 32-lane node group)
  const float4 xv = *(const float4*)(x + (size_t)node * 128 + q * 4);
  float4 r;
  r.x = acc0.x + acc1.x + xv.x;
  r.y = acc0.y + acc1.y + xv.y;
  r.z = acc0.z + acc1.z + xv.z;
  r.w = acc0.w + acc1.w + xv.w;
  float s1 = r.x + r.y + r.z + r.w;
  float s2 = r.x*r.x + r.y*r.y + r.z*r.z + r.w*r.w;
  #pragma unroll
  for (int off = 16; off; off >>= 1) {    // xor masks stay within the 32-half
    s1 += __shfl_xor(s1, off);
    s2 += __shfl_xor(s2, off);
  }
  const float mu   = s1 * (1.f / 128.f);
  const float var  = s2 * (1.f / 128.f) - mu * mu;
  const float rstd = rsqrtf(var + LN_EPS);
  const float4 g4 = *(const float4*)(gamma + q * 4);
  const float4 b4 = *(const float4*)(beta  + q * 4);
  float4 o;
  o.x = (r.x - mu) * rstd * g4.x + b4.x;
  o.y = (r.y - mu) * rstd * g4.y + b4.y;
  o.z = (r.z - mu) * rstd * g4.z + b4.z;
  o.w = (r.w - mu) * rstd * g4.w + b4.w;
  o.x = o.x > 0.f ? o.x : expm1f(o.x);
  o.y = o.y > 0.f ? o.y : expm1f(o.y);
  o.z = o.z > 0.f ? o.z : expm1f(o.z);
  o.w = o.w > 0.f ? o.w : expm1f(o.w);
  *(float4*)(out + (size_t)node * 128 + q * 4) = o;
}

// ---------------------------------------------------------------------------
extern "C" void kernel_launch(void* const* d_in, const int* in_sizes, int n_in,
                              void* d_out, int out_size, void* d_ws, size_t ws_size,
                              hipStream_t stream)
{
  const float* x    = (const float*)d_in[0];
  const int*   ei   = (const int*)d_in[1];
  const float* W    = (const float*)d_in[2];
  const float* a_s  = (const float*)d_in[3];
  const float* a_d  = (const float*)d_in[4];
  const float* gam  = (const float*)d_in[5];
  const float* bet  = (const float*)d_in[6];
  float* out = (float*)d_out;

  const int n_nodes = in_sizes[0] / 128;
  const int n_edges = in_sizes[1] / 2;
  const int* e_src = ei;
  const int* e_dst = ei + n_edges;

  // workspace carve-up (~35 MB)
  char* p = (char*)d_ws;
  unsigned* h = (unsigned*)p; p += (size_t)n_nodes * 64 * sizeof(unsigned);  // bf16-packed
  float* ssrc = (float*)p;  p += (size_t)n_nodes * 4 * sizeof(float);
  float* sdst = (float*)p;  p += (size_t)n_nodes * 4 * sizeof(float);
  int* counts    = (int*)p; p += (size_t)n_nodes * sizeof(int);
  int* row_start = (int*)p; p += (size_t)(n_nodes + 4) * sizeof(int);
  int* blk_sums  = (int*)p; p += 128 * sizeof(int);
  int* cursor    = (int*)p; p += (size_t)n_nodes * sizeof(int);
  int* csr_src   = (int*)p; p += (size_t)n_edges * sizeof(int);

  hipMemsetAsync(counts, 0, (size_t)n_nodes * sizeof(int), stream);

  const int nproj  = (n_nodes + 31) / 32;
  const int ncount = (n_edges + 1023) / 1024;
  k_proj_count<<<nproj + ncount, 256, 0, stream>>>(
      x, W, a_s, a_d, h, ssrc, sdst, n_nodes, e_dst, counts, n_edges, nproj);
  const int nblk = (n_nodes + 1023) / 1024;
  k_scan1<<<nblk, 256, 0, stream>>>(counts, row_start, blk_sums, n_nodes);
  k_scan2<<<1, 128, 0, stream>>>(blk_sums, nblk, row_start, n_nodes, n_edges);
  k_scan3<<<nblk, 256, 0, stream>>>(row_start, blk_sums, cursor, n_nodes);
  k_fill<<<(n_edges + 255) / 256, 256, 0, stream>>>(e_src, e_dst, cursor, csr_src, n_edges);
  k_agg<<<(n_nodes + 7) / 8, 256, 0, stream>>>(h, ssrc, sdst, row_start, csr_src, x, gam, bet, out, n_nodes);
}

// Round 4
// 261.863 us; speedup vs baseline: 1.5004x; 1.1107x over previous
//
#include <hip/hip_runtime.h>
#include <math.h>

#define NEG_SLOPE 0.2f
#define LN_EPS 1e-5f

typedef __attribute__((ext_vector_type(8))) short bf16x8;
typedef __attribute__((ext_vector_type(4))) float f32x4;

// fp32 -> bf16 (RTNE)
static __device__ __forceinline__ unsigned short f2bf(float f) {
  unsigned u = __float_as_uint(f);
  u += 0x7fffu + ((u >> 16) & 1u);
  return (unsigned short)(u >> 16);
}
static __device__ __forceinline__ float bf2f(unsigned short b) {
  return __uint_as_float((unsigned)b << 16);
}
// pack two fp32 into bf16x2 (RTNE), elem0 in low half
static __device__ __forceinline__ unsigned pack_bf16(float a, float b) {
  unsigned ua = __float_as_uint(a);
  unsigned ub = __float_as_uint(b);
  ua += 0x7fffu + ((ua >> 16) & 1u);
  ub += 0x7fffu + ((ub >> 16) & 1u);
  return (ua >> 16) | (ub & 0xffff0000u);
}
static __device__ __forceinline__ float bf_lo(unsigned u) { return __uint_as_float(u << 16); }
static __device__ __forceinline__ float bf_hi(unsigned u) { return __uint_as_float(u & 0xffff0000u); }

// ---------------------------------------------------------------------------
// k_proj_count: MFMA projection (split-bf16: h = x_hi@W + x_lo@W) + fused
// degree-count role blocks.
//  Proj blocks: 128 rows each (4 waves x 2 row-tiles of 16). W staged once in
//  LDS in B-fragment order (32 KB bf16, conflict-free b128). Per (ctile,kk):
//  1 ds_read_b128 B-frag -> 4 MFMA (2 row-tiles x {hi,lo}).
//  h stored bf16-packed via 2 shfl_xor pack steps (uint2 stores).
//  mfma_f32_16x16x32_bf16 layouts (HW-verified, guide §3):
//    A: lane holds A[m=lane&15][k=(lane>>4)*8+j]   (j=0..7)
//    B: lane holds B[k=(lane>>4)*8+j][n=lane&15]
//    C/D: lane holds D[row=(lane>>4)*4+reg][col=lane&15]
// ---------------------------------------------------------------------------
__global__ __launch_bounds__(256) void k_proj_count(
    const float* __restrict__ x, const float* __restrict__ W,
    unsigned* __restrict__ h, int n_nodes,
    const int* __restrict__ e_dst, int* __restrict__ counts,
    int n_edges, int nproj)
{
  __shared__ __align__(16) short wlds[32 * 64 * 8];   // 32 KB: [ctile*4+kk][lane][8]

  if (blockIdx.x >= nproj) {
    // ---- count role: 4 edges per thread via int4 (fire-and-forget atomics)
    int e = ((blockIdx.x - nproj) * 256 + threadIdx.x) * 4;
    if (e + 4 <= n_edges) {
      const int4 d = *(const int4*)(e_dst + e);
      atomicAdd(&counts[d.x], 1);
      atomicAdd(&counts[d.y], 1);
      atomicAdd(&counts[d.z], 1);
      atomicAdd(&counts[d.w], 1);
    } else {
      for (; e < n_edges; ++e) atomicAdd(&counts[e_dst[e]], 1);
    }
    return;
  }

  const int t    = threadIdx.x;
  const int l    = t & 63;        // lane in wave
  const int il   = l & 15;
  const int quad = l >> 4;
  const int wbase = blockIdx.x * 128 + (t >> 6) * 32;   // wave's 32 rows

  // ---- stage W into LDS in B-fragment order (bf16)
  for (int idx = t; idx < 2048; idx += 256) {
    const int tile = idx >> 6;          // ctile*4 + kk
    const int l2   = idx & 63;
    const int c    = tile >> 2;
    const int kk   = tile & 3;
    const int q2   = l2 >> 4;
    const int i2   = l2 & 15;
    const float* wp = W + (size_t)(kk * 32 + q2 * 8) * 128 + c * 16 + i2;
    bf16x8 wv;
    #pragma unroll
    for (int j = 0; j < 8; ++j) wv[j] = (short)f2bf(wp[(size_t)j * 128]);
    *(bf16x8*)(wlds + idx * 8) = wv;
  }

  // ---- load + convert A fragments (x rows), split hi/lo bf16
  bf16x8 ahi[2][4], alo[2][4];
  #pragma unroll
  for (int rt = 0; rt < 2; ++rt) {
    int row = wbase + rt * 16 + il;
    if (row > n_nodes - 1) row = n_nodes - 1;    // clamp (dup row, stores guarded)
    #pragma unroll
    for (int kk = 0; kk < 4; ++kk) {
      const float* p = x + (size_t)row * 128 + kk * 32 + quad * 8;
      const float4 u0 = *(const float4*)(p);
      const float4 u1 = *(const float4*)(p + 4);
      float f[8] = {u0.x, u0.y, u0.z, u0.w, u1.x, u1.y, u1.z, u1.w};
      #pragma unroll
      for (int j = 0; j < 8; ++j) {
        const unsigned short hb = f2bf(f[j]);
        ahi[rt][kk][j] = (short)hb;
        alo[rt][kk][j] = (short)f2bf(f[j] - bf2f(hb));
      }
    }
  }

  __syncthreads();

  // ---- MFMA main: acc[rt][c] over 8 col-tiles, K=128 in 4 steps, 2 terms
  f32x4 acc[2][8] = {};
  #pragma unroll
  for (int c = 0; c < 8; ++c) {
    #pragma unroll
    for (int kk = 0; kk < 4; ++kk) {
      const bf16x8 b = *(const bf16x8*)(wlds + ((c * 4 + kk) * 64 + l) * 8);
      acc[0][c] = __builtin_amdgcn_mfma_f32_16x16x32_bf16(ahi[0][kk], b, acc[0][c], 0, 0, 0);
      acc[0][c] = __builtin_amdgcn_mfma_f32_16x16x32_bf16(alo[0][kk], b, acc[0][c], 0, 0, 0);
      acc[1][c] = __builtin_amdgcn_mfma_f32_16x16x32_bf16(ahi[1][kk], b, acc[1][c], 0, 0, 0);
      acc[1][c] = __builtin_amdgcn_mfma_f32_16x16x32_bf16(alo[1][kk], b, acc[1][c], 0, 0, 0);
    }
  }

  // ---- epilogue: pack to bf16 pairs across il-neighbors, store uint2
  #pragma unroll
  for (int rt = 0; rt < 2; ++rt) {
    #pragma unroll
    for (int reg = 0; reg < 4; ++reg) {
      const int r = wbase + rt * 16 + quad * 4 + reg;
      const bool wr = (r < n_nodes) && ((il & 3) == 0);
      #pragma unroll
      for (int c = 0; c < 8; ++c) {
        const float v  = acc[rt][c][reg];
        const float vn = __shfl_xor(v, 1);
        const float plo = (il & 1) ? vn : v;
        const float phi = (il & 1) ? v : vn;
        const unsigned px = pack_bf16(plo, phi);     // pair (il&~1, il&~1+1)
        const unsigned py = __shfl_xor(px, 2);       // pair from il^2
        if (wr) {
          uint2 u; u.x = px; u.y = py;
          *(uint2*)(h + (size_t)r * 64 + c * 8 + (il >> 1)) = u;
        }
      }
    }
  }
}

// ---------------------------------------------------------------------------
// k_scan: single-dispatch exclusive scan of counts -> row_start (+cursor),
// decoupled lookback. desc[b] packs (flag<<62)|value: 1=AGG, 2=INC, 0=invalid
// (memset). All 98 blocks co-resident (<< 256 CUs) -> lookback terminates.
// ---------------------------------------------------------------------------
__global__ __launch_bounds__(256) void k_scan(
    const int* __restrict__ counts, int n, int n_edges,
    int* __restrict__ row_start, int* __restrict__ cursor,
    unsigned long long* __restrict__ desc)
{
  __shared__ int sdata[256];
  __shared__ int s_prefix;
  const int b = blockIdx.x, t = threadIdx.x;
  const int base = b * 1024 + t * 4;
  const int v0 = (base+0 < n) ? counts[base+0] : 0;
  const int v1 = (base+1 < n) ? counts[base+1] : 0;
  const int v2 = (base+2 < n) ? counts[base+2] : 0;
  const int v3 = (base+3 < n) ? counts[base+3] : 0;
  const int tsum = v0 + v1 + v2 + v3;
  sdata[t] = tsum;
  __syncthreads();
  for (int off = 1; off < 256; off <<= 1) {
    const int addv = (t >= off) ? sdata[t - off] : 0;
    __syncthreads();
    sdata[t] += addv;
    __syncthreads();
  }
  const int block_total = sdata[255];
  const int local_excl  = sdata[t] - tsum;

  // publish AGG (or INC for block 0) ASAP
  if (t == 0) {
    if (b == 0) {
      atomicExch(&desc[0], (2ULL << 62) | (unsigned long long)block_total);
      s_prefix = 0;
    } else {
      atomicExch(&desc[b], (1ULL << 62) | (unsigned long long)block_total);
    }
  }

  // parallel lookback by wave 0
  if (b > 0 && t < 64) {
    int jbase = b - 1;
    int accum = 0;
    for (;;) {
      const int j = jbase - t;
      unsigned long long d = (j >= 0) ? atomicAdd(&desc[j], 0ULL) : (2ULL << 62);
      const unsigned flag = (unsigned)(d >> 62);
      const unsigned long long m_inc  = __ballot(flag == 2);
      const unsigned long long m_zero = __ballot(flag == 0);
      const int kinc = (m_inc == 0) ? 64 : (__ffsll((long long)m_inc) - 1);
      const unsigned long long below = (kinc >= 64) ? ~0ULL : ((1ULL << kinc) - 1ULL);
      if (m_zero & below) continue;                 // a predecessor not yet published
      int contrib = (t <= kinc) ? (int)(d & 0x3FFFFFFFFFFFFFFFULL) : 0;
      #pragma unroll
      for (int off = 32; off; off >>= 1) contrib += __shfl_xor(contrib, off);
      accum += contrib;
      if (kinc < 64) break;
      jbase -= 64;
    }
    if (t == 0) {
      s_prefix = accum;
      atomicExch(&desc[b], (2ULL << 62) | (unsigned long long)(accum + block_total));
    }
  }
  __syncthreads();
  const int prefix = s_prefix;

  int excl = prefix + local_excl;
  if (base+0 < n) { row_start[base+0] = excl; cursor[base+0] = excl; }  excl += v0;
  if (base+1 < n) { row_start[base+1] = excl; cursor[base+1] = excl; }  excl += v1;
  if (base+2 < n) { row_start[base+2] = excl; cursor[base+2] = excl; }  excl += v2;
  if (base+3 < n) { row_start[base+3] = excl; cursor[base+3] = excl; }
  if (b == 0 && t == 0) row_start[n] = n_edges;
}

// ---------------------------------------------------------------------------
// k_fill_ssrc: role-split.
//  Blocks [0, nfill): CSR fill, 1 edge/thread (returning atomics want TLP).
//  Blocks [nfill, ...): per-node attention scalars from bf16 h:
//    ssrc[n][head] = sum_d h[n,head,d]*a_src[d]  (32 lanes/node, 8/head).
// ---------------------------------------------------------------------------
__global__ __launch_bounds__(256) void k_fill_ssrc(
    const int* __restrict__ src, const int* __restrict__ dst,
    int* __restrict__ cursor, int* __restrict__ csr_src, int n_edges,
    const unsigned* __restrict__ h, const float* __restrict__ a_src,
    const float* __restrict__ a_dst, float* __restrict__ ssrc,
    float* __restrict__ sdst, int n_nodes, int nfill)
{
  if (blockIdx.x < nfill) {
    const int e = blockIdx.x * 256 + threadIdx.x;
    if (e < n_edges) {
      const int pos = atomicAdd(&cursor[dst[e]], 1);
      csr_src[pos] = src[e];
    }
    return;
  }
  const int t    = threadIdx.x;
  const int lane = t & 63;
  const int q    = lane & 31;
  const int node = (blockIdx.x - nfill) * 8 + (t >> 6) * 2 + (lane >> 5);
  if (node >= n_nodes) return;
  const uint2 hh = *(const uint2*)(h + (size_t)node * 64 + q * 2);
  const float b0 = bf_lo(hh.x), b1 = bf_hi(hh.x), b2 = bf_lo(hh.y), b3 = bf_hi(hh.y);
  const float4 as4 = *(const float4*)(a_src + (q & 7) * 4);
  const float4 ad4 = *(const float4*)(a_dst + (q & 7) * 4);
  float ps = b0*as4.x + b1*as4.y + b2*as4.z + b3*as4.w;
  float pd = b0*ad4.x + b1*ad4.y + b2*ad4.z + b3*ad4.w;
  #pragma unroll
  for (int off = 1; off < 8; off <<= 1) {
    ps += __shfl_xor(ps, off);
    pd += __shfl_xor(pd, off);
  }
  if ((q & 7) == 0) {
    const int head = q >> 3;
    ssrc[node * 4 + head] = ps;
    sdst[node * 4 + head] = pd;
  }
}

// ---------------------------------------------------------------------------
// k_agg: 32 lanes per node (block 256 = 8 nodes). Lane q owns d = 4q..4q+3.
// Phase A: 8-lane head groups, online softmax stats; s stashed for edges
//          0..15 (covers deg<=16, ~99.6% of Poisson(8) nodes).
// Phase B: unroll-2 alpha-weighted gather of bf16-packed h (dwordx2/lane).
// Epilogue: residual + LayerNorm (32-lane shfl) + ELU. No LDS/atomics.
// ---------------------------------------------------------------------------
__global__ __launch_bounds__(256) void k_agg(
    const unsigned* __restrict__ h, const float* __restrict__ ssrc,
    const float* __restrict__ sdst, const int* __restrict__ row_start,
    const int* __restrict__ csr_src, const float* __restrict__ x,
    const float* __restrict__ gamma, const float* __restrict__ beta,
    float* __restrict__ out, int n_nodes)
{
  const int t    = threadIdx.x;
  const int lane = t & 63;
  const int q    = lane & 31;
  const int node = blockIdx.x * 8 + (t >> 6) * 2 + (lane >> 5);
  if (node >= n_nodes) return;           // uniform per 32-lane half
  const int head = q >> 3;
  const int beg  = row_start[node];
  const int deg  = row_start[node + 1] - beg;
  const float sd = sdst[node * 4 + head];

  // Phase A: online max/sum over strided edge subset (8 lanes per head)
  float m = -INFINITY, l = 0.f;
  float sk0 = 0.f, sk1 = 0.f;            // stash: s for edges (q&7), (q&7)+8
  for (int i = (q & 7); i < deg; i += 8) {
    const int src = csr_src[beg + i];
    float s = ssrc[src * 4 + head] + sd;
    s = s > 0.f ? s : NEG_SLOPE * s;
    if (i < 8) sk0 = s; else if (i < 16) sk1 = s;
    const float mn = fmaxf(m, s);
    l = l * __expf(m - mn) + __expf(s - mn);
    m = mn;
  }
  #pragma unroll
  for (int off = 1; off < 8; off <<= 1) {   // merge within 8-lane head group
    const float m2 = __shfl_xor(m, off);
    const float l2 = __shfl_xor(l, off);
    const float mn = fmaxf(m, m2);
    if (mn == -INFINITY) { m = -INFINITY; l = 0.f; }
    else {
      l = l * __expf(m - mn) + l2 * __expf(m2 - mn);
      m = mn;
    }
  }
  const float inv_l = (deg > 0) ? 1.f / l : 0.f;
  const int  sbase  = lane & 56;         // 32-half base | (q&24)
  const bool small  = (deg <= 16);

  // Phase B: unrolled weighted bf16 gather (uint2 = 4 bf16 per lane)
  float4 acc0 = make_float4(0.f, 0.f, 0.f, 0.f);
  float4 acc1 = make_float4(0.f, 0.f, 0.f, 0.f);
  int i = 0;
  for (; i + 2 <= deg; i += 2) {
    const int srcA = csr_src[beg + i];
    const int srcB = csr_src[beg + i + 1];
    const uint2 hA = *(const uint2*)(h + (size_t)srcA * 64 + q * 2);
    const uint2 hB = *(const uint2*)(h + (size_t)srcB * 64 + q * 2);
    float sA, sB;
    if (small) {
      const float svA = (i & 8) ? sk1 : sk0;
      const float svB = ((i + 1) & 8) ? sk1 : sk0;
      sA = __shfl(svA, sbase | (i & 7));
      sB = __shfl(svB, sbase | ((i + 1) & 7));
    } else {
      float a = ssrc[srcA * 4 + head] + sd; sA = a > 0.f ? a : NEG_SLOPE * a;
      float b = ssrc[srcB * 4 + head] + sd; sB = b > 0.f ? b : NEG_SLOPE * b;
    }
    const float alA = __expf(sA - m) * inv_l;
    const float alB = __expf(sB - m) * inv_l;
    acc0.x = fmaf(alA, bf_lo(hA.x), acc0.x);
    acc0.y = fmaf(alA, bf_hi(hA.x), acc0.y);
    acc0.z = fmaf(alA, bf_lo(hA.y), acc0.z);
    acc0.w = fmaf(alA, bf_hi(hA.y), acc0.w);
    acc1.x = fmaf(alB, bf_lo(hB.x), acc1.x);
    acc1.y = fmaf(alB, bf_hi(hB.x), acc1.y);
    acc1.z = fmaf(alB, bf_lo(hB.y), acc1.z);
    acc1.w = fmaf(alB, bf_hi(hB.y), acc1.w);
  }
  if (i < deg) {                          // tail edge
    const int srcA = csr_src[beg + i];
    const uint2 hA = *(const uint2*)(h + (size_t)srcA * 64 + q * 2);
    float sA;
    if (small) {
      const float svA = (i & 8) ? sk1 : sk0;
      sA = __shfl(svA, sbase | (i & 7));
    } else {
      float a = ssrc[srcA * 4 + head] + sd; sA = a > 0.f ? a : NEG_SLOPE * a;
    }
    const float alA = __expf(sA - m) * inv_l;
    acc0.x = fmaf(alA, bf_lo(hA.x), acc0.x);
    acc0.y = fmaf(alA, bf_hi(hA.x), acc0.y);
    acc0.z = fmaf(alA, bf_lo(hA.y), acc0.z);
    acc0.w = fmaf(alA, bf_hi(hA.y), acc0.w);
  }

  // residual + LayerNorm + ELU (all within the 32-lane node group)
  const float4 xv = *(const float4*)(x + (size_t)node * 128 + q * 4);
  float4 r;
  r.x = acc0.x + acc1.x + xv.x;
  r.y = acc0.y + acc1.y + xv.y;
  r.z = acc0.z + acc1.z + xv.z;
  r.w = acc0.w + acc1.w + xv.w;
  float s1 = r.x + r.y + r.z + r.w;
  float s2 = r.x*r.x + r.y*r.y + r.z*r.z + r.w*r.w;
  #pragma unroll
  for (int off = 16; off; off >>= 1) {    // xor masks stay within the 32-half
    s1 += __shfl_xor(s1, off);
    s2 += __shfl_xor(s2, off);
  }
  const float mu   = s1 * (1.f / 128.f);
  const float var  = s2 * (1.f / 128.f) - mu * mu;
  const float rstd = rsqrtf(var + LN_EPS);
  const float4 g4 = *(const float4*)(gamma + q * 4);
  const float4 b4 = *(const float4*)(beta  + q * 4);
  float4 o;
  o.x = (r.x - mu) * rstd * g4.x + b4.x;
  o.y = (r.y - mu) * rstd * g4.y + b4.y;
  o.z = (r.z - mu) * rstd * g4.z + b4.z;
  o.w = (r.w - mu) * rstd * g4.w + b4.w;
  o.x = o.x > 0.f ? o.x : expm1f(o.x);
  o.y = o.y > 0.f ? o.y : expm1f(o.y);
  o.z = o.z > 0.f ? o.z : expm1f(o.z);
  o.w = o.w > 0.f ? o.w : expm1f(o.w);
  *(float4*)(out + (size_t)node * 128 + q * 4) = o;
}

// ---------------------------------------------------------------------------
extern "C" void kernel_launch(void* const* d_in, const int* in_sizes, int n_in,
                              void* d_out, int out_size, void* d_ws, size_t ws_size,
                              hipStream_t stream)
{
  const float* x    = (const float*)d_in[0];
  const int*   ei   = (const int*)d_in[1];
  const float* W    = (const float*)d_in[2];
  const float* a_s  = (const float*)d_in[3];
  const float* a_d  = (const float*)d_in[4];
  const float* gam  = (const float*)d_in[5];
  const float* bet  = (const float*)d_in[6];
  float* out = (float*)d_out;

  const int n_nodes = in_sizes[0] / 128;
  const int n_edges = in_sizes[1] / 2;
  const int* e_src = ei;
  const int* e_dst = ei + n_edges;

  const int nblk = (n_nodes + 1023) / 1024;    // scan blocks

  // workspace carve-up (~33 MB). counts+desc contiguous for one memset.
  char* p = (char*)d_ws;
  unsigned* h = (unsigned*)p; p += (size_t)n_nodes * 64 * sizeof(unsigned);  // bf16-packed
  float* ssrc = (float*)p;  p += (size_t)n_nodes * 4 * sizeof(float);
  float* sdst = (float*)p;  p += (size_t)n_nodes * 4 * sizeof(float);
  int* counts = (int*)p;    p += (size_t)((n_nodes + 1) & ~1) * sizeof(int); // 8B-align next
  unsigned long long* desc = (unsigned long long*)p; p += (size_t)nblk * sizeof(unsigned long long);
  int* row_start = (int*)p; p += (size_t)(n_nodes + 4) * sizeof(int);
  int* cursor    = (int*)p; p += (size_t)n_nodes * sizeof(int);
  int* csr_src   = (int*)p; p += (size_t)n_edges * sizeof(int);

  const size_t zero_bytes = (char*)(desc + nblk) - (char*)counts;
  hipMemsetAsync(counts, 0, zero_bytes, stream);

  const int nproj  = (n_nodes + 127) / 128;
  const int ncount = (n_edges + 1023) / 1024;
  k_proj_count<<<nproj + ncount, 256, 0, stream>>>(
      x, W, h, n_nodes, e_dst, counts, n_edges, nproj);
  k_scan<<<nblk, 256, 0, stream>>>(counts, n_nodes, n_edges, row_start, cursor, desc);
  const int nfill = (n_edges + 255) / 256;
  const int nsrcb = (n_nodes + 7) / 8;
  k_fill_ssrc<<<nfill + nsrcb, 256, 0, stream>>>(
      e_src, e_dst, cursor, csr_src, n_edges, h, a_s, a_d, ssrc, sdst, n_nodes, nfill);
  k_agg<<<(n_nodes + 7) / 8, 256, 0, stream>>>(h, ssrc, sdst, row_start, csr_src, x, gam, bet, out, n_nodes);
}